// Round 1
// baseline (65.339 us; speedup 1.0000x reference)
//
#include <hip/hip_runtime.h>
#include <math.h>

#define NB 32
#define NC 256
#define SH 56
#define SW 56
#define HW 3136      // 56*56
#define HW4 784      // HW/4

// ---------------------------------------------------------------------------
// Kernel 1: per-(b,p) channel max & mean over C=256.
// Block = 256 threads = 32 float4 spatial positions x 8 channel-groups (32 ch).
// Grid = (B*HW4)/32 = 784 blocks.
// ---------------------------------------------------------------------------
__global__ __launch_bounds__(256) void k_reduce(const float4* __restrict__ x,
                                                float4* __restrict__ mx_out,
                                                float4* __restrict__ av_out) {
    __shared__ float4 smax[8][32];
    __shared__ float4 ssum[8][32];
    const int tid = threadIdx.x;
    const int pos = tid & 31;
    const int cg  = tid >> 5;
    const unsigned g = blockIdx.x * 32u + pos;       // global float4 spatial idx
    const int b  = (int)(g / HW4);
    const int p4 = (int)(g - (unsigned)b * HW4);
    const float4* base = x + ((size_t)b * NC) * HW4 + p4 + (size_t)(cg * 32) * HW4;

    const float NEG = -__builtin_inff();
    float4 vmax = make_float4(NEG, NEG, NEG, NEG);
    float4 vsum = make_float4(0.f, 0.f, 0.f, 0.f);
    #pragma unroll 8
    for (int c = 0; c < 32; ++c) {
        float4 v = base[(size_t)c * HW4];
        vmax.x = fmaxf(vmax.x, v.x); vmax.y = fmaxf(vmax.y, v.y);
        vmax.z = fmaxf(vmax.z, v.z); vmax.w = fmaxf(vmax.w, v.w);
        vsum.x += v.x; vsum.y += v.y; vsum.z += v.z; vsum.w += v.w;
    }
    smax[cg][pos] = vmax;
    ssum[cg][pos] = vsum;
    __syncthreads();
    if (tid < 32) {
        float4 m = smax[0][tid];
        float4 s = ssum[0][tid];
        #pragma unroll
        for (int q = 1; q < 8; ++q) {
            float4 mm = smax[q][tid];
            float4 ss = ssum[q][tid];
            m.x = fmaxf(m.x, mm.x); m.y = fmaxf(m.y, mm.y);
            m.z = fmaxf(m.z, mm.z); m.w = fmaxf(m.w, mm.w);
            s.x += ss.x; s.y += ss.y; s.z += ss.z; s.w += ss.w;
        }
        const float r = 1.0f / 256.0f;
        s.x *= r; s.y *= r; s.z *= r; s.w *= r;
        const unsigned go = blockIdx.x * 32u + tid;
        mx_out[go] = m;
        av_out[go] = s;
    }
}

// ---------------------------------------------------------------------------
// Kernel 2: 7x7 conv (2ch->1ch, pad 3) + folded BN + sigmoid -> gate [B][HW].
// Grid = B*HW/256 = 392 blocks exactly.
// ---------------------------------------------------------------------------
__global__ __launch_bounds__(256) void k_conv(const float* __restrict__ mx,
                                              const float* __restrict__ av,
                                              const float* __restrict__ cw,
                                              const float* __restrict__ gamma,
                                              const float* __restrict__ beta,
                                              const float* __restrict__ rmean,
                                              const float* __restrict__ rvar,
                                              float* __restrict__ gate) {
    __shared__ float swm[49];   // BN-scaled weights, channel 0 (max)
    __shared__ float swa[49];   // BN-scaled weights, channel 1 (avg)
    __shared__ float sbias;
    const int tid = threadIdx.x;
    const float inv = gamma[0] * rsqrtf(rvar[0] + 1e-5f);
    if (tid < 49)                swm[tid]      = cw[tid]      * inv;
    else if (tid < 98)           swa[tid - 49] = cw[tid]      * inv;
    if (tid == 0)                sbias = beta[0] - rmean[0] * inv;
    __syncthreads();

    const int idx = blockIdx.x * 256 + tid;          // over B*HW (exact)
    const int b = idx / HW;
    const int p = idx - b * HW;
    const int h = p / SW;
    const int w = p - h * SW;
    const float* mrow = mx + (size_t)b * HW;
    const float* arow = av + (size_t)b * HW;

    float acc = sbias;
    #pragma unroll
    for (int kh = 0; kh < 7; ++kh) {
        const int hh = h + kh - 3;
        if (hh < 0 || hh >= SH) continue;
        #pragma unroll
        for (int kw = 0; kw < 7; ++kw) {
            const int ww = w + kw - 3;
            if (ww < 0 || ww >= SW) continue;
            const int q = hh * SW + ww;
            acc += mrow[q] * swm[kh * 7 + kw] + arow[q] * swa[kh * 7 + kw];
        }
    }
    gate[idx] = 1.0f / (1.0f + expf(-acc));
}

// ---------------------------------------------------------------------------
// Kernel 3: out[b,c,p] = x[b,c,p] * gate[b,p], float4-vectorized, grid-stride.
// ---------------------------------------------------------------------------
__global__ __launch_bounds__(256) void k_mul(const float4* __restrict__ x,
                                             const float4* __restrict__ gate,  // [B][HW4]
                                             float4* __restrict__ out) {
    const unsigned total = (unsigned)NB * NC * HW4;  // 6,422,528 float4
    const unsigned stride = gridDim.x * 256u;
    for (unsigned v = blockIdx.x * 256u + threadIdx.x; v < total; v += stride) {
        const unsigned row = v / HW4;                // b*C + c
        const unsigned p4  = v - row * HW4;
        const unsigned b   = row >> 8;               // /256
        const float4 g4 = gate[b * HW4 + p4];
        const float4 xv = x[v];
        out[v] = make_float4(xv.x * g4.x, xv.y * g4.y, xv.z * g4.z, xv.w * g4.w);
    }
}

extern "C" void kernel_launch(void* const* d_in, const int* in_sizes, int n_in,
                              void* d_out, int out_size, void* d_ws, size_t ws_size,
                              hipStream_t stream) {
    const float* x     = (const float*)d_in[0];
    const float* cw    = (const float*)d_in[1];
    const float* gamma = (const float*)d_in[2];
    const float* beta  = (const float*)d_in[3];
    const float* rmean = (const float*)d_in[4];
    const float* rvar  = (const float*)d_in[5];
    float* out = (float*)d_out;

    // Workspace layout (floats): mx [B*HW] | av [B*HW] | gate [B*HW]
    float* mx_p   = (float*)d_ws;
    float* av_p   = mx_p + (size_t)NB * HW;
    float* gate_p = av_p + (size_t)NB * HW;

    // K1: channel max/mean
    k_reduce<<<(NB * HW4) / 32, 256, 0, stream>>>(
        (const float4*)x, (float4*)mx_p, (float4*)av_p);

    // K2: conv + BN + sigmoid -> gate
    k_conv<<<(NB * HW) / 256, 256, 0, stream>>>(
        mx_p, av_p, cw, gamma, beta, rmean, rvar, gate_p);

    // K3: broadcast multiply
    k_mul<<<2048, 256, 0, stream>>>(
        (const float4*)x, (const float4*)gate_p, (float4*)out);
}

// Round 2
// 63.097 us; speedup vs baseline: 1.0355x; 1.0355x over previous
//
#include <hip/hip_runtime.h>
#include <math.h>

#define NB 32
#define NC 256
#define SH 56
#define SW 56
#define HW 3136      // 56*56
#define HW4 784      // HW/4

// ---------------------------------------------------------------------------
// Kernel 1: per-(b,p) channel max & mean over C=256.
// Block = 256 threads = 32 float4 spatial positions x 8 channel-groups (32 ch).
// Grid = (B*HW4)/32 = 784 blocks. Each wave reads 2x512B contiguous segments
// (full 64B lines) per load instruction.
// ---------------------------------------------------------------------------
__global__ __launch_bounds__(256) void k_reduce(const float4* __restrict__ x,
                                                float4* __restrict__ mx_out,
                                                float4* __restrict__ av_out) {
    __shared__ float4 smax[8][32];
    __shared__ float4 ssum[8][32];
    const int tid = threadIdx.x;
    const int pos = tid & 31;
    const int cg  = tid >> 5;
    const unsigned g = blockIdx.x * 32u + pos;       // global float4 spatial idx
    const int b  = (int)(g / HW4);
    const int p4 = (int)(g - (unsigned)b * HW4);
    const float4* base = x + ((size_t)b * NC) * HW4 + p4 + (size_t)(cg * 32) * HW4;

    const float NEG = -__builtin_inff();
    float4 vmax = make_float4(NEG, NEG, NEG, NEG);
    float4 vsum = make_float4(0.f, 0.f, 0.f, 0.f);
    #pragma unroll 8
    for (int c = 0; c < 32; ++c) {
        float4 v = base[(size_t)c * HW4];
        vmax.x = fmaxf(vmax.x, v.x); vmax.y = fmaxf(vmax.y, v.y);
        vmax.z = fmaxf(vmax.z, v.z); vmax.w = fmaxf(vmax.w, v.w);
        vsum.x += v.x; vsum.y += v.y; vsum.z += v.z; vsum.w += v.w;
    }
    smax[cg][pos] = vmax;
    ssum[cg][pos] = vsum;
    __syncthreads();
    if (tid < 32) {
        float4 m = smax[0][tid];
        float4 s = ssum[0][tid];
        #pragma unroll
        for (int q = 1; q < 8; ++q) {
            float4 mm = smax[q][tid];
            float4 ss = ssum[q][tid];
            m.x = fmaxf(m.x, mm.x); m.y = fmaxf(m.y, mm.y);
            m.z = fmaxf(m.z, mm.z); m.w = fmaxf(m.w, mm.w);
            s.x += ss.x; s.y += ss.y; s.z += ss.z; s.w += ss.w;
        }
        const float r = 1.0f / 256.0f;
        s.x *= r; s.y *= r; s.z *= r; s.w *= r;
        const unsigned go = blockIdx.x * 32u + tid;
        mx_out[go] = m;
        av_out[go] = s;
    }
}

// ---------------------------------------------------------------------------
// Kernel 2 (fused conv+BN+sigmoid+multiply):
// Block = (batch b, row-pair rp) -> rows 2rp, 2rp+1 (112 positions).
// Phase A: 112 threads compute gate for the strip from mx/av (L2-warm) -> LDS.
// Phase B: all 256 threads stream 256 channels x 28 float4 of x, multiply by
//          LDS gate, write out. Grid = 32*28 = 896 blocks (3.5/CU).
// ---------------------------------------------------------------------------
__global__ __launch_bounds__(256) void k_conv_mul(const float* __restrict__ mx,
                                                  const float* __restrict__ av,
                                                  const float* __restrict__ cw,
                                                  const float* __restrict__ gamma,
                                                  const float* __restrict__ beta,
                                                  const float* __restrict__ rmean,
                                                  const float* __restrict__ rvar,
                                                  const float4* __restrict__ x,
                                                  float4* __restrict__ out) {
    __shared__ float sw[98];       // BN-scaled weights: [0..48]=max ch, [49..97]=avg ch
    __shared__ float sbias;
    __shared__ float4 sgate4[28];  // 112 gate floats for this strip

    const int tid = threadIdx.x;
    const int b  = blockIdx.x / 28;
    const int rp = blockIdx.x - b * 28;              // row pair: rows 2rp, 2rp+1

    const float inv = gamma[0] * rsqrtf(rvar[0] + 1e-5f);
    if (tid < 98) sw[tid] = cw[tid] * inv;
    if (tid == 0) sbias = beta[0] - rmean[0] * inv;
    __syncthreads();

    if (tid < 112) {
        const int h = rp * 2 + (tid / 56 ? 1 : 0) + 0 * tid;  // row within image
        const int hr = rp * 2 + (tid >= 56 ? 1 : 0);
        const int w  = tid - (tid >= 56 ? 56 : 0);
        const float* mrow = mx + (size_t)b * HW;
        const float* arow = av + (size_t)b * HW;
        float acc = sbias;
        #pragma unroll
        for (int kh = 0; kh < 7; ++kh) {
            const int hh = hr + kh - 3;
            if (hh < 0 || hh >= SH) continue;
            #pragma unroll
            for (int kw = 0; kw < 7; ++kw) {
                const int ww = w + kw - 3;
                if (ww < 0 || ww >= SW) continue;
                const int q = hh * SW + ww;
                acc += mrow[q] * sw[kh * 7 + kw] + arow[q] * sw[49 + kh * 7 + kw];
            }
        }
        ((float*)sgate4)[tid] = 1.0f / (1.0f + expf(-acc));
        (void)h;
    }
    __syncthreads();

    // Phase B: 256 ch x 28 float4 = 7168 float4 per block, 28 iterations.
    const size_t strip = (size_t)b * NC * HW4 + (size_t)rp * 28;
    #pragma unroll 4
    for (int it = 0; it < 28; ++it) {
        const unsigned idx = (unsigned)it * 256u + (unsigned)tid;  // 0..7167
        const unsigned c = idx / 28u;
        const unsigned q = idx - c * 28u;
        const size_t off = strip + (size_t)c * HW4 + q;
        const float4 g  = sgate4[q];
        const float4 xv = x[off];
        out[off] = make_float4(xv.x * g.x, xv.y * g.y, xv.z * g.z, xv.w * g.w);
    }
}

extern "C" void kernel_launch(void* const* d_in, const int* in_sizes, int n_in,
                              void* d_out, int out_size, void* d_ws, size_t ws_size,
                              hipStream_t stream) {
    const float* x     = (const float*)d_in[0];
    const float* cw    = (const float*)d_in[1];
    const float* gamma = (const float*)d_in[2];
    const float* beta  = (const float*)d_in[3];
    const float* rmean = (const float*)d_in[4];
    const float* rvar  = (const float*)d_in[5];
    float* out = (float*)d_out;

    // Workspace layout (floats): mx [B*HW] | av [B*HW]
    float* mx_p = (float*)d_ws;
    float* av_p = mx_p + (size_t)NB * HW;

    // K1: channel max/mean
    k_reduce<<<(NB * HW4) / 32, 256, 0, stream>>>(
        (const float4*)x, (float4*)mx_p, (float4*)av_p);

    // K2: conv + BN + sigmoid + broadcast multiply (fused)
    k_conv_mul<<<NB * 28, 256, 0, stream>>>(
        mx_p, av_p, cw, gamma, beta, rmean, rvar,
        (const float4*)x, (float4*)out);
}